// Round 12
// baseline (5245.846 us; speedup 1.0000x reference)
//
#include <hip/hip_runtime.h>

// ---------------------------------------------------------------------------
// PolicyNetRSNNPB forward, MI355X/gfx950.  Round 21: permlane dedup via the
// BUILTIN (hand-asm abandoned), poll reverted to r18 exact-match.
// History: r18 passed (k_rec 3575 us; LDS weight stream = binding constraint:
// 2048 ds_read_b64/CU-step, lanes l and l+32 read IDENTICAL weights).
// r19 failed (asm operand aliasing -> self-swap). r20 failed (absmax 0.64:
// v_mov writes the swap's source in the immediately preceding instruction
// inside one asm block -> cross-lane wait-state hazard the compiler can't
// see; permlane family needs compiler-managed hazards).
// THIS ROUND: __builtin_amdgcn_permlane32_swap(x, x, false, false) -> v2i.
// Under EITHER hardware swap direction, {r[0],r[1]} = {lo-half broadcast,
// hi-half broadcast}; a one-time lane-id probe picks which index is lo.
// __has_builtin guard + unknown-direction fallback = r18 two-load path.
// Poll compare reverted to r18's (v>>16)!=expct so the ONLY behavioral
// change vs the passing r18 is the weight fetch.
//   KGROUP: 1x ds_read_b64 + 2 permlane + 12 VALU per 4k (r18: 2x b64 + 12)
//   -> CU-step LDS instrs 2048 -> 1024.
// Everything else byte-identical to r18: mixed-role blocks (4 rec + 4 ff
// waves, 1+1 per SIMD), 1 tagged mask16 word/thread poll, ZERO per-step
// barriers, parity ring + no-reuse hist, ballot stores, memset-zeroed tags,
// setprio(1) rec.
// Arithmetic FROZEN (numpy-fp32 emulation), BIT-EXACT to r10..r18: ascending
// k per accumulator, K split [0,384)+[384,512) merged by one fadd; bit=1 ->
// fadd(acc,w), bit=0 -> fadd(acc,+0); epilogue single-rounded identical.
// ---------------------------------------------------------------------------

typedef unsigned int       u32;
typedef unsigned short     u16;
typedef unsigned long long u64;
typedef unsigned char      u8;
typedef int v2i __attribute__((ext_vector_type(2)));

#define TSTEPS 512
#define HIDDEN 512

// workspace layout (bytes) — unchanged from r18.
#define XW_OFF    0ull
#define C3_OFF    0ull
#define MEM_OFF   33554432ull
#define RING_OFF  67108864ull
#define HIST_OFF  68157440ull
#define SPKB_OFF  83886080ull
#define WT_OFF    109051904ull
#define WINT_OFF  109314048ull
#define WS_NEED   (134742016ull + 4096ull)

#define WSTRIDE 514   // dwords; bank step 2 on the weight stream

#if defined(__has_builtin)
#if __has_builtin(__builtin_amdgcn_permlane32_swap)
#define HAVE_PLSWAP 1
#endif
#endif
#ifndef HAVE_PLSWAP
#define HAVE_PLSWAP 0
#endif

// ---------------------------------------------------------------------------
__global__ __launch_bounds__(256) void k_prepT(
    const float* __restrict__ Win,
    const float* __restrict__ Wmu, const float* __restrict__ Wlv,
    float* __restrict__ WinT, float* __restrict__ WT)
{
  const int idx = blockIdx.x * 256 + threadIdx.x;
  if (idx < 65536) {
    const int k = idx >> 9, j = idx & 511;
    WinT[idx] = Win[j * 128 + k];
  } else {
    const int i2 = idx - 65536;
    const int k = i2 >> 7, j = i2 & 127;
    WT[i2] = (j < 64) ? Wmu[j * 512 + k] : Wlv[(j - 64) * 512 + k];
  }
}

// ---------------------------------------------------------------------------
// k_xw: XW[(t2*128 + n)*512 + j] row-major (k_rec lanes read coalesced 128B).
// ---------------------------------------------------------------------------
__global__ __launch_bounds__(256) void k_xw(
    const float* __restrict__ state, const float* __restrict__ target,
    const float* __restrict__ WinT, const float* __restrict__ b_in,
    float* __restrict__ XW)
{
  __shared__ float xs[16][129];
  const int tid  = threadIdx.x;
  const int row0 = blockIdx.x * 16;

  for (int e = tid; e < 2048; e += 256) {
    int r = e >> 7, k = e & 127;
    xs[r][k] = (k < 64) ? state[(row0 + r) * 64 + k]
                        : target[(row0 + r) * 64 + k - 64];
  }
  __syncthreads();

#pragma unroll
  for (int jh = 0; jh < 2; ++jh) {
    const int j = jh * 256 + tid;
    float acc[16];
#pragma unroll
    for (int r = 0; r < 16; ++r) acc[r] = 0.0f;
    for (int k = 0; k < 128; ++k) {
      const float wv = WinT[k * 512 + j];
#pragma unroll
      for (int r = 0; r < 16; ++r)
        acc[r] = __builtin_fmaf(xs[r][k], wv, acc[r]);
    }
    const float b = b_in[j];
#pragma unroll
    for (int r = 0; r < 16; ++r)
      XW[(u64)(row0 + r) * 512 + j] = __fadd_rn(acc[r], b);
  }
}

#if HAVE_PLSWAP
// one k4-group with permlane-shared weights; LOI/HII pick which swap result
// is the lo-half / hi-half broadcast (determined by the one-time probe).
#define KGROUP(ACC, LOI, HII)                                                \
  {                                                                          \
    const float2 wv = *(const float2*)(lanew + d * 32 + k4);                 \
    const v2i r0 = __builtin_amdgcn_permlane32_swap(                         \
        __float_as_int(wv.x), __float_as_int(wv.x), false, false);           \
    const v2i r1 = __builtin_amdgcn_permlane32_swap(                         \
        __float_as_int(wv.y), __float_as_int(wv.y), false, false);           \
    ACC = __fadd_rn(ACC, __int_as_float(                                     \
        __builtin_amdgcn_sbfe(word, k4 + 0, 1) & r0[LOI]));                  \
    ACC = __fadd_rn(ACC, __int_as_float(                                     \
        __builtin_amdgcn_sbfe(word, k4 + 1, 1) & r1[LOI]));                  \
    ACC = __fadd_rn(ACC, __int_as_float(                                     \
        __builtin_amdgcn_sbfe(word, k4 + 2, 1) & r0[HII]));                  \
    ACC = __fadd_rn(ACC, __int_as_float(                                     \
        __builtin_amdgcn_sbfe(word, k4 + 3, 1) & r1[HII]));                  \
  }
#endif

// r18 fallback group: every lane reads all 4 dwords itself (broadcast-free,
// 2x ds_read_b64) — bit-exact, r18 speed.
#define KGROUPF(ACC)                                                         \
  {                                                                          \
    const float2 wa = *(const float2*)(WLrow + d * 32 + k4);                 \
    const float2 wb = *(const float2*)(WLrow + d * 32 + k4 + 2);             \
    ACC = __fadd_rn(ACC, __int_as_float(                                     \
        __builtin_amdgcn_sbfe(word, k4 + 0, 1) & __float_as_int(wa.x)));     \
    ACC = __fadd_rn(ACC, __int_as_float(                                     \
        __builtin_amdgcn_sbfe(word, k4 + 1, 1) & __float_as_int(wa.y)));     \
    ACC = __fadd_rn(ACC, __int_as_float(                                     \
        __builtin_amdgcn_sbfe(word, k4 + 2, 1) & __float_as_int(wb.x)));     \
    ACC = __fadd_rn(ACC, __int_as_float(                                     \
        __builtin_amdgcn_sbfe(word, k4 + 3, 1) & __float_as_int(wb.y)));     \
  }

#define MACLOOPS(GROUPA, GROUPB)                                             \
  {                                                                          \
    _Pragma("unroll")                                                        \
    for (int d = 0; d < 12; ++d) {                                           \
      const int word = (int)bw[d];                                           \
      _Pragma("unroll")                                                      \
      for (int k4 = 0; k4 < 32; k4 += 4) GROUPA                              \
    }                                                                        \
    _Pragma("unroll")                                                        \
    for (int d = 12; d < 16; ++d) {                                          \
      const int word = (int)bw[d];                                           \
      _Pragma("unroll")                                                      \
      for (int k4 = 0; k4 < 32; k4 += 4) GROUPB                              \
    }                                                                        \
  }

// ---------------------------------------------------------------------------
// k_rec: grid 256 x 512 threads; block = (rg 0..15: 8 rows, c 0..15: 32
// units); waves 0-3 rec, waves 4-7 ff (1 rec + 1 ff per SIMD).
// ---------------------------------------------------------------------------
__global__ __launch_bounds__(512, 2) void k_rec(
    const float* __restrict__ XW,
    const float* __restrict__ Wrec, const float* __restrict__ Wff,
    const float* __restrict__ alpha_rec, const float* __restrict__ beta_rec,
    const float* __restrict__ b_rec,
    const float* __restrict__ b_ff, const float* __restrict__ alpha_ff,
    const float* __restrict__ beta_ff,
    u32* __restrict__ ring32, u32* __restrict__ hist32,
    u16* __restrict__ spkb16)
{
  __shared__ __align__(16) float WR[32 * WSTRIDE];  // 65792 B
  __shared__ __align__(16) float WF[32 * WSTRIDE];  // 65792 B
  __shared__ __align__(16) u16 MBr[8][32];          //   512 B
  __shared__ __align__(16) u16 MBf[8][32];          //   512 B -> 132608 total
                                                    // (forces 1 block/CU)

  const int tid  = threadIdx.x;
  const int w    = tid >> 6;            // wave 0..7
  const int l    = tid & 63;            // lane
  const bool isFF = (w >= 4);
  const int wl   = w & 3;               // wave within role 0..3
  const int rg   = blockIdx.x >> 4;     // row group 0..15 (8 rows each)
  const int c    = blockIdx.x & 15;     // unit chunk 0..15 (32 units)
  const int u    = l & 31;              // unit within chunk
  const int rp   = l >> 5;              // row within wave pair
  const int rl   = 2 * wl + rp;         // local row 0..7
  const int g    = 8 * rg + rl;         // global batch row 0..127
  const int jj   = 32 * c + u;          // hidden unit
  const int widx = l & 31;              // polled word index 0..31

  // stage BOTH weight tiles: stride 514 dwords, float2 granularity
  for (int it = tid; it < 8192; it += 512) {
    const int uu = it >> 8, m2 = (it & 255) * 2;
    *(float2*)(WR + uu * WSTRIDE + m2) =
        *(const float2*)(Wrec + (u64)(32 * c + uu) * 512 + m2);
    *(float2*)(WF + uu * WSTRIDE + m2) =
        *(const float2*)(Wff + (u64)(32 * c + uu) * 512 + m2);
  }

  const float coA = isFF ? alpha_ff[jj] : alpha_rec[jj];
  const float coB = isFF ? beta_ff[jj]  : beta_rec[jj];
  const float coC = isFF ? b_ff[jj]     : b_rec[jj];

  const float* WLrow = (isFF ? WF : WR) + u * WSTRIDE;  // full-row base
  const float* lanew = WLrow + 2 * rp;                  // half-k base

  u16* MBrow = (isFF ? MBf : MBr)[rl];

  // ---- probe permlane32_swap direction (wave-uniform, once, builtin) ----
  // Under either direction {res[0],res[1]} = {lo-half bcast, hi-half bcast}
  // possibly swapped; classify via lane-id pattern.
  int dmode = 2;
#if HAVE_PLSWAP
  {
    const v2i pr = __builtin_amdgcn_permlane32_swap((int)l, (int)l,
                                                    false, false);
    const int a0  = __builtin_amdgcn_readlane(pr[0], 0);
    const int a32 = __builtin_amdgcn_readlane(pr[0], 32);
    const int b0  = __builtin_amdgcn_readlane(pr[1], 0);
    const int b32 = __builtin_amdgcn_readlane(pr[1], 32);
    if (a0 == 0 && a32 == 0 && b0 == 32 && b32 == 32)      dmode = 0;
    else if (a0 == 32 && a32 == 32 && b0 == 0 && b32 == 0) dmode = 1;
  }
#endif

  float syn = 0.f, mem = 0.f, spk = 0.f, xw = 0.f;

  __syncthreads();  // weights ready (the ONLY barrier)

  if (!isFF) __builtin_amdgcn_s_setprio(1);  // rec clique = critical path

#pragma unroll 1
  for (int s = 0; s < TSTEPS; ++s) {
    const bool doMac = isFF || (s > 0);

    if (doMac) {
      // ---- poll ONE tagged word (own row g, word widx); r18 exact-match ----
      u32 v;
      if (!isFF) {
        const u32 expct = (u32)s;                   // stored end of step s-1
        const u32* src = ring32 + ((s - 1) & 1) * 4096 + g * 32 + widx;
        v = __hip_atomic_load(src, __ATOMIC_RELAXED, __HIP_MEMORY_SCOPE_AGENT);
        while ((v >> 16) != expct) {
          __builtin_amdgcn_s_sleep(1);
          v = __hip_atomic_load(src, __ATOMIC_RELAXED, __HIP_MEMORY_SCOPE_AGENT);
        }
      } else {
        const u32 expct = (u32)(s + 1);             // rec stores hist[s] tag s+1
        const u32* src = hist32 + (u64)s * 4096 + g * 32 + widx;
        v = __hip_atomic_load(src, __ATOMIC_RELAXED, __HIP_MEMORY_SCOPE_AGENT);
        while ((v >> 16) != expct) {
          __builtin_amdgcn_s_sleep(1);
          v = __hip_atomic_load(src, __ATOMIC_RELAXED, __HIP_MEMORY_SCOPE_AGENT);
        }
      }
      MBrow[widx] = (u16)v;   // wave-private row; program order suffices
    }

    if (!isFF && !(s & 1))             // x reused across REPEAT=2
      xw = XW[((u64)(s >> 1) * 128 + g) * 512 + jj];

    float SA = 0.f;
    if (doMac) {
      // own row's 512 spike bits (written by own wave's lanes; dense 64B)
      const uint4* bq = (const uint4*)MBrow;
      const uint4 q0 = bq[0], q1 = bq[1], q2 = bq[2], q3 = bq[3];
      const u32 bw[16] = { q0.x, q0.y, q0.z, q0.w, q1.x, q1.y, q1.z, q1.w,
                           q2.x, q2.y, q2.z, q2.w, q3.x, q3.y, q3.z, q3.w };
      float aA = 0.f, aB = 0.f;
      // BLAS-faithful: ascending k, split at k=384 (d=12), one merge fadd.
#if HAVE_PLSWAP
      if (dmode == 0) {
        MACLOOPS(KGROUP(aA, 0, 1), KGROUP(aB, 0, 1))
      } else if (dmode == 1) {
        MACLOOPS(KGROUP(aA, 1, 0), KGROUP(aB, 1, 0))
      } else {
        MACLOOPS(KGROUPF(aA), KGROUPF(aB))
      }
#else
      MACLOOPS(KGROUPF(aA), KGROUPF(aB))
#endif
      SA = __fadd_rn(aA, aB);
    }

    // epilogue (single-rounded, identical op sequence to r10..r18)
    const float cur = isFF ? __fadd_rn(SA, coC)
                           : __fadd_rn(__fadd_rn(xw, SA), coC);
    syn = __fadd_rn(__fmul_rn(coA, syn), cur);
    mem = __fsub_rn(__fadd_rn(__fmul_rn(coB, mem), syn), spk);
    spk = (mem > 1.0f) ? 1.0f : 0.0f;

    // per-wave ballot store: bits 0..31 = row 2wl, bits 32..63 = row 2wl+1
    const u64 B = __ballot(spk != 0.f);
    const int rowbase = 8 * rg + 2 * wl;
    if (!isFF) {
      if (l < 4) {
        const u32 word = (u32)(B >> (16 * l)) & 0xFFFFu;
        const int gs = rowbase + (l >> 1);
        const int wx = 2 * c + (l & 1);
        __hip_atomic_store(ring32 + (s & 1) * 4096 + gs * 32 + wx,
                           ((u32)(s + 1) << 16) | word,
                           __ATOMIC_RELAXED, __HIP_MEMORY_SCOPE_AGENT);
      } else if (l < 8) {
        const int l2 = l - 4;
        const u32 word = (u32)(B >> (16 * l2)) & 0xFFFFu;
        const int gs = rowbase + (l2 >> 1);
        const int wx = 2 * c + (l2 & 1);
        __hip_atomic_store(hist32 + (u64)s * 4096 + gs * 32 + wx,
                           ((u32)(s + 1) << 16) | word,
                           __ATOMIC_RELAXED, __HIP_MEMORY_SCOPE_AGENT);
      }
    } else {
      if (l < 4) {
        const u32 word = (u32)(B >> (16 * l)) & 0xFFFFu;
        const int gs = rowbase + (l >> 1);
        const int wx = 2 * c + (l & 1);
        spkb16[(u64)s * 4096 + gs * 32 + wx] = (u16)word;
      }
    }
    // no end-of-step barrier: staging rows are wave-private; poll gating
    // bounds skew (reaching store(s) requires poll(s) success, which requires
    // every clique wave of this row finished reading step s-2's slot).
  }
}

// ---------------------------------------------------------------------------
// k_c3: ff spike history (mask16 words) @ W_mu/W_lv readout, + bias.
// Same ascending-k FMA order (k = 16*wi + kk), split at wi=24 (k=384).
// ---------------------------------------------------------------------------
__global__ __launch_bounds__(256) void k_c3(
    const u16* __restrict__ spkb16, const float* __restrict__ WT,
    const float* __restrict__ bmu, const float* __restrict__ blv,
    float* __restrict__ c3)
{
  __shared__ __align__(8) u16 Bc[32][36];  // [row-local][32 w16, pad 36]
  const int tid   = threadIdx.x;
  const int rows0 = blockIdx.x * 32;

  {
    const int r = tid >> 3, gq = tid & 7;   // 32 rows x 8B
    const u64 vv = *(const u64*)(spkb16 + (u64)(rows0 + r) * 32 + 4 * gq);
    *(u64*)&Bc[r][4 * gq] = vv;
  }
  __syncthreads();

  const int j  = tid & 127;
  const int rh = tid >> 7;
  const float bias = (j < 64) ? bmu[j] : blv[j - 64];

  float accA[16], accB[16];
#pragma unroll
  for (int r = 0; r < 16; ++r) { accA[r] = 0.f; accB[r] = 0.f; }

  for (int wi = 0; wi < 24; ++wi) {   // k = 16*wi + kk < 384
    u16 wrow[16];
#pragma unroll
    for (int r = 0; r < 16; ++r) wrow[r] = Bc[rh * 16 + r][wi];
    const float* wpp = WT + (wi * 16) * 128 + j;
#pragma unroll
    for (int kk = 0; kk < 16; ++kk) {
      const float wvv = wpp[kk * 128];
#pragma unroll
      for (int r = 0; r < 16; ++r) {
        const float b = (float)((wrow[r] >> kk) & 1u);
        accA[r] = __builtin_fmaf(b, wvv, accA[r]);
      }
    }
  }
  for (int wi = 24; wi < 32; ++wi) {  // k >= 384
    u16 wrow[16];
#pragma unroll
    for (int r = 0; r < 16; ++r) wrow[r] = Bc[rh * 16 + r][wi];
    const float* wpp = WT + (wi * 16) * 128 + j;
#pragma unroll
    for (int kk = 0; kk < 16; ++kk) {
      const float wvv = wpp[kk * 128];
#pragma unroll
      for (int r = 0; r < 16; ++r) {
        const float b = (float)((wrow[r] >> kk) & 1u);
        accB[r] = __builtin_fmaf(b, wvv, accB[r]);
      }
    }
  }

#pragma unroll
  for (int r = 0; r < 16; ++r)
    c3[(u64)(rows0 + rh * 16 + r) * 128 + j] =
        __fadd_rn(__fadd_rn(accA[r], accB[r]), bias);
}

// ---------------------------------------------------------------------------
__global__ __launch_bounds__(256) void k_scan(
    const float* __restrict__ c3,
    const float* __restrict__ beta_mu, const float* __restrict__ beta_lv,
    float* __restrict__ Mem)
{
  const int tid = blockIdx.x * 256 + threadIdx.x;
  const int n = tid >> 7, ap = tid & 127;
  const float beta = (ap < 64) ? beta_mu[ap] : beta_lv[ap - 64];
  const float* src = c3 + n * 128 + ap;
  float* dst = Mem + n * 128 + ap;
  float mem = 0.0f;
  for (int t = 0; t < 512; ++t) {
    mem = __fadd_rn(__fmul_rn(beta, mem), src[(u64)t * 16384]);
    dst[(u64)t * 16384] = mem;
  }
}

// ---------------------------------------------------------------------------
__global__ __launch_bounds__(256) void k_out(
    const float* __restrict__ Mem,
    const float* __restrict__ Wmu_out, const float* __restrict__ Wlv_out,
    float* __restrict__ out)
{
  const int tid = blockIdx.x * 256 + threadIdx.x;
  const int a = tid & 7;
  const int n = (tid >> 3) & 127;
  const int t = (tid >> 10) & 255;
  const int kind = tid >> 18;
  const float* wv = ((kind == 0) ? Wmu_out : Wlv_out) + a * 64;
  const float* s0 = Mem + ((u64)(2 * t) * 128 + n) * 128 + kind * 64;
  const float* s1 = Mem + ((u64)(2 * t + 1) * 128 + n) * 128 + kind * 64;
  float mu0 = 0.0f, mu1 = 0.0f;
#pragma unroll 8
  for (int q = 0; q < 64; ++q) mu0 = __builtin_fmaf(s0[q], wv[q], mu0);
#pragma unroll 8
  for (int q = 0; q < 64; ++q) mu1 = __builtin_fmaf(s1[q], wv[q], mu1);
  out[tid] = __fmul_rn(__fadd_rn(mu0, mu1), 0.5f);
}

// ---------------------------------------------------------------------------
extern "C" void kernel_launch(void* const* d_in, const int* in_sizes, int n_in,
                              void* d_out, int out_size, void* d_ws, size_t ws_size,
                              hipStream_t stream) {
  (void)in_sizes; (void)n_in; (void)out_size;
  if (ws_size < WS_NEED) return;

  const float* state     = (const float*)d_in[0];
  const float* target    = (const float*)d_in[1];
  const float* W_rec_in  = (const float*)d_in[2];
  const float* b_rec_in  = (const float*)d_in[3];
  const float* W_rec     = (const float*)d_in[4];
  const float* b_rec     = (const float*)d_in[5];
  const float* alpha_rec = (const float*)d_in[6];
  const float* beta_rec  = (const float*)d_in[7];
  const float* W_ff_in   = (const float*)d_in[8];
  const float* b_ff_in   = (const float*)d_in[9];
  const float* alpha_ff  = (const float*)d_in[10];
  const float* beta_ff   = (const float*)d_in[11];
  const float* W_mu_in   = (const float*)d_in[12];
  const float* b_mu_in   = (const float*)d_in[13];
  const float* beta_mu   = (const float*)d_in[14];
  const float* W_mu_out  = (const float*)d_in[15];
  const float* W_lv_in   = (const float*)d_in[16];
  const float* b_lv_in   = (const float*)d_in[17];
  const float* beta_lv   = (const float*)d_in[18];
  const float* W_lv_out  = (const float*)d_in[19];

  char* ws = (char*)d_ws;
  float* XW    = (float*)(ws + XW_OFF);
  float* c3    = (float*)(ws + C3_OFF);
  float* Mem   = (float*)(ws + MEM_OFF);
  u32*   ring32= (u32*)  (ws + RING_OFF);
  u32*   hist32= (u32*)  (ws + HIST_OFF);
  u16*   spkb16= (u16*)  (ws + SPKB_OFF);
  float* WT    = (float*)(ws + WT_OFF);
  float* WinT  = (float*)(ws + WINT_OFF);

  // zero the tagged regions so tags (>=1) can never false-match poison
  hipMemsetAsync(ws + RING_OFF, 0, 32768, stream);
  hipMemsetAsync(ws + HIST_OFF, 0, 8388608, stream);

  hipLaunchKernelGGL(k_prepT, dim3(512), dim3(256), 0, stream,
                     W_rec_in, W_mu_in, W_lv_in, WinT, WT);
  hipLaunchKernelGGL(k_xw, dim3(2048), dim3(256), 0, stream,
                     state, target, WinT, b_rec_in, XW);
  hipLaunchKernelGGL(k_rec, dim3(256), dim3(512), 0, stream,
                     XW, W_rec, W_ff_in,
                     alpha_rec, beta_rec, b_rec,
                     b_ff_in, alpha_ff, beta_ff, ring32, hist32, spkb16);
  hipLaunchKernelGGL(k_c3, dim3(2048), dim3(256), 0, stream,
                     spkb16, WT, b_mu_in, b_lv_in, c3);
  hipLaunchKernelGGL(k_scan, dim3(64), dim3(256), 0, stream,
                     c3, beta_mu, beta_lv, Mem);
  hipLaunchKernelGGL(k_out, dim3(2048), dim3(256), 0, stream,
                     Mem, W_mu_out, W_lv_out, (float*)d_out);
}

// Round 13
// 4093.435 us; speedup vs baseline: 1.2815x; 1.2815x over previous
//
#include <hip/hip_runtime.h>

// ---------------------------------------------------------------------------
// PolicyNetRSNNPB forward, MI355X/gfx950.  Round 22: b128 weight stream.
// r21 (permlane dedup) passed but REGRESSED (4990 vs r18 3575): the builtin's
// codegen bloated the MAC to ~9 VALU/k (VALUBusy 89.7%) — trading 1 LDS instr
// for >2 VALU is a loss. Permlane abandoned; base = r18 (best passing).
// Refined model: r18 step 7.0 us = LDS issue (~5 us/CU-step, 2048 b64) +
// exchange (~2 us), VALU (2.6 us) hidden underneath. THIS ROUND cuts LDS
// INSTRUCTIONS in half at identical VALU: WSTRIDE 514 -> 516 (16B-aligned
// rows) and 2x float2 -> 1x float4 (ds_read_b128) per 4k. The old "4-way
// conflict at 516" objection applies to b64 only: a b128 across 32 unique
// addrs moves 512B = 4 LDS cycles BY BANDWIDTH; the 4-way serialization at
// stride 516 coincides with that floor (no extra penalty). Same weights,
// same ascending-k fadd chain -> bit-exact. SQ_LDS_BANK_CONFLICT will RISE
// (counts the BW-floor serialization) — expected, benign.
// Everything else byte-identical to r18: mixed-role blocks (4 rec + 4 ff
// waves, 1+1 per SIMD), 1 tagged mask16 word/thread poll (exact-match),
// ZERO per-step barriers, parity ring + no-reuse hist, ballot stores,
// memset-zeroed tags, setprio(1) rec.
// Arithmetic FROZEN (numpy-fp32 emulation), BIT-EXACT to r10..r18: ascending
// k per accumulator, K split [0,384)+[384,512) merged by one fadd; bit=1 ->
// fadd(acc,w), bit=0 -> fadd(acc,+0); epilogue single-rounded identical.
// ---------------------------------------------------------------------------

typedef unsigned int       u32;
typedef unsigned short     u16;
typedef unsigned long long u64;
typedef unsigned char      u8;

#define TSTEPS 512
#define HIDDEN 512

// workspace layout (bytes) — unchanged from r18.
#define XW_OFF    0ull
#define C3_OFF    0ull
#define MEM_OFF   33554432ull
#define RING_OFF  67108864ull
#define HIST_OFF  68157440ull
#define SPKB_OFF  83886080ull
#define WT_OFF    109051904ull
#define WINT_OFF  109314048ull
#define WS_NEED   (134742016ull + 4096ull)

#define WSTRIDE 516   // dwords; 16B-aligned rows -> ds_read_b128 legal.
                      // b128 4-way bank serialization == BW floor (benign).

// ---------------------------------------------------------------------------
__global__ __launch_bounds__(256) void k_prepT(
    const float* __restrict__ Win,
    const float* __restrict__ Wmu, const float* __restrict__ Wlv,
    float* __restrict__ WinT, float* __restrict__ WT)
{
  const int idx = blockIdx.x * 256 + threadIdx.x;
  if (idx < 65536) {
    const int k = idx >> 9, j = idx & 511;
    WinT[idx] = Win[j * 128 + k];
  } else {
    const int i2 = idx - 65536;
    const int k = i2 >> 7, j = i2 & 127;
    WT[i2] = (j < 64) ? Wmu[j * 512 + k] : Wlv[(j - 64) * 512 + k];
  }
}

// ---------------------------------------------------------------------------
// k_xw: XW[(t2*128 + n)*512 + j] row-major (k_rec lanes read coalesced 128B).
// ---------------------------------------------------------------------------
__global__ __launch_bounds__(256) void k_xw(
    const float* __restrict__ state, const float* __restrict__ target,
    const float* __restrict__ WinT, const float* __restrict__ b_in,
    float* __restrict__ XW)
{
  __shared__ float xs[16][129];
  const int tid  = threadIdx.x;
  const int row0 = blockIdx.x * 16;

  for (int e = tid; e < 2048; e += 256) {
    int r = e >> 7, k = e & 127;
    xs[r][k] = (k < 64) ? state[(row0 + r) * 64 + k]
                        : target[(row0 + r) * 64 + k - 64];
  }
  __syncthreads();

#pragma unroll
  for (int jh = 0; jh < 2; ++jh) {
    const int j = jh * 256 + tid;
    float acc[16];
#pragma unroll
    for (int r = 0; r < 16; ++r) acc[r] = 0.0f;
    for (int k = 0; k < 128; ++k) {
      const float wv = WinT[k * 512 + j];
#pragma unroll
      for (int r = 0; r < 16; ++r)
        acc[r] = __builtin_fmaf(xs[r][k], wv, acc[r]);
    }
    const float b = b_in[j];
#pragma unroll
    for (int r = 0; r < 16; ++r)
      XW[(u64)(row0 + r) * 512 + j] = __fadd_rn(acc[r], b);
  }
}

// ---------------------------------------------------------------------------
// k_rec: grid 256 x 512 threads; block = (rg 0..15: 8 rows, c 0..15: 32
// units); waves 0-3 rec, waves 4-7 ff (1 rec + 1 ff per SIMD).
// Per wave per step (NO barriers): poll own tagged mask16 word -> u16 LDS
// write (wave-private row) -> uint4 bit reads -> MAC (ds_read_b128 weight
// stream, sbfe+and+fadd, 3 VALU/MAC) -> epilogue -> ballot -> stores.
// ---------------------------------------------------------------------------
__global__ __launch_bounds__(512, 2) void k_rec(
    const float* __restrict__ XW,
    const float* __restrict__ Wrec, const float* __restrict__ Wff,
    const float* __restrict__ alpha_rec, const float* __restrict__ beta_rec,
    const float* __restrict__ b_rec,
    const float* __restrict__ b_ff, const float* __restrict__ alpha_ff,
    const float* __restrict__ beta_ff,
    u32* __restrict__ ring32, u32* __restrict__ hist32,
    u16* __restrict__ spkb16)
{
  __shared__ __align__(16) float WR[32 * WSTRIDE];  // 66048 B
  __shared__ __align__(16) float WF[32 * WSTRIDE];  // 66048 B
  __shared__ __align__(16) u16 MBr[8][32];          //   512 B
  __shared__ __align__(16) u16 MBf[8][32];          //   512 B -> 133120 total
                                                    // (forces 1 block/CU)

  const int tid  = threadIdx.x;
  const int w    = tid >> 6;            // wave 0..7
  const int l    = tid & 63;            // lane
  const bool isFF = (w >= 4);
  const int wl   = w & 3;               // wave within role 0..3
  const int rg   = blockIdx.x >> 4;     // row group 0..15 (8 rows each)
  const int c    = blockIdx.x & 15;     // unit chunk 0..15 (32 units)
  const int u    = l & 31;              // unit within chunk
  const int rp   = l >> 5;              // row within wave pair
  const int rl   = 2 * wl + rp;         // local row 0..7
  const int g    = 8 * rg + rl;         // global batch row 0..127
  const int jj   = 32 * c + u;          // hidden unit
  const int widx = l & 31;              // polled word index 0..31

  // stage BOTH weight tiles: stride 516 dwords, float4 granularity
  for (int it = tid; it < 4096; it += 512) {
    const int uu = it >> 7, m4 = (it & 127) * 4;
    *(float4*)(WR + uu * WSTRIDE + m4) =
        *(const float4*)(Wrec + (u64)(32 * c + uu) * 512 + m4);
    *(float4*)(WF + uu * WSTRIDE + m4) =
        *(const float4*)(Wff + (u64)(32 * c + uu) * 512 + m4);
  }

  const float coA = isFF ? alpha_ff[jj] : alpha_rec[jj];
  const float coB = isFF ? beta_ff[jj]  : beta_rec[jj];
  const float coC = isFF ? b_ff[jj]     : b_rec[jj];

  const float* WLrow = (isFF ? WF : WR) + u * WSTRIDE;
  u16* MBrow = (isFF ? MBf : MBr)[rl];

  float syn = 0.f, mem = 0.f, spk = 0.f, xw = 0.f;

  __syncthreads();  // weights ready (the ONLY barrier)

  if (!isFF) __builtin_amdgcn_s_setprio(1);  // rec clique = critical path

#pragma unroll 1
  for (int s = 0; s < TSTEPS; ++s) {
    const bool doMac = isFF || (s > 0);

    if (doMac) {
      // ---- poll ONE tagged word (own row g, word widx); exact-match ----
      u32 v;
      if (!isFF) {
        const u32 expct = (u32)s;                   // stored end of step s-1
        const u32* src = ring32 + ((s - 1) & 1) * 4096 + g * 32 + widx;
        v = __hip_atomic_load(src, __ATOMIC_RELAXED, __HIP_MEMORY_SCOPE_AGENT);
        while ((v >> 16) != expct) {
          __builtin_amdgcn_s_sleep(1);
          v = __hip_atomic_load(src, __ATOMIC_RELAXED, __HIP_MEMORY_SCOPE_AGENT);
        }
      } else {
        const u32 expct = (u32)(s + 1);             // rec stores hist[s] tag s+1
        const u32* src = hist32 + (u64)s * 4096 + g * 32 + widx;
        v = __hip_atomic_load(src, __ATOMIC_RELAXED, __HIP_MEMORY_SCOPE_AGENT);
        while ((v >> 16) != expct) {
          __builtin_amdgcn_s_sleep(1);
          v = __hip_atomic_load(src, __ATOMIC_RELAXED, __HIP_MEMORY_SCOPE_AGENT);
        }
      }
      MBrow[widx] = (u16)v;   // wave-private row; program order suffices
    }

    if (!isFF && !(s & 1))             // x reused across REPEAT=2
      xw = XW[((u64)(s >> 1) * 128 + g) * 512 + jj];

    float SA = 0.f;
    if (doMac) {
      // own row's 512 spike bits (written by own wave's lanes; dense 64B)
      const uint4* bq = (const uint4*)MBrow;
      const uint4 q0 = bq[0], q1 = bq[1], q2 = bq[2], q3 = bq[3];
      const u32 bw[16] = { q0.x, q0.y, q0.z, q0.w, q1.x, q1.y, q1.z, q1.w,
                           q2.x, q2.y, q2.z, q2.w, q3.x, q3.y, q3.z, q3.w };
      float aA = 0.f, aB = 0.f;
      // BLAS-faithful: ascending k, split at k=384 (d=12), one merge fadd.
      // Per 4k: 1x ds_read_b128 + 4x (sbfe + and + fadd).
#pragma unroll
      for (int d = 0; d < 12; ++d) {
        const int word = (int)bw[d];
#pragma unroll
        for (int k4 = 0; k4 < 32; k4 += 4) {
          const float4 w4 = *(const float4*)(WLrow + d * 32 + k4);
          aA = __fadd_rn(aA, __int_as_float(
              __builtin_amdgcn_sbfe(word, k4 + 0, 1) & __float_as_int(w4.x)));
          aA = __fadd_rn(aA, __int_as_float(
              __builtin_amdgcn_sbfe(word, k4 + 1, 1) & __float_as_int(w4.y)));
          aA = __fadd_rn(aA, __int_as_float(
              __builtin_amdgcn_sbfe(word, k4 + 2, 1) & __float_as_int(w4.z)));
          aA = __fadd_rn(aA, __int_as_float(
              __builtin_amdgcn_sbfe(word, k4 + 3, 1) & __float_as_int(w4.w)));
        }
      }
#pragma unroll
      for (int d = 12; d < 16; ++d) {
        const int word = (int)bw[d];
#pragma unroll
        for (int k4 = 0; k4 < 32; k4 += 4) {
          const float4 w4 = *(const float4*)(WLrow + d * 32 + k4);
          aB = __fadd_rn(aB, __int_as_float(
              __builtin_amdgcn_sbfe(word, k4 + 0, 1) & __float_as_int(w4.x)));
          aB = __fadd_rn(aB, __int_as_float(
              __builtin_amdgcn_sbfe(word, k4 + 1, 1) & __float_as_int(w4.y)));
          aB = __fadd_rn(aB, __int_as_float(
              __builtin_amdgcn_sbfe(word, k4 + 2, 1) & __float_as_int(w4.z)));
          aB = __fadd_rn(aB, __int_as_float(
              __builtin_amdgcn_sbfe(word, k4 + 3, 1) & __float_as_int(w4.w)));
        }
      }
      SA = __fadd_rn(aA, aB);
    }

    // epilogue (single-rounded, identical op sequence to r10..r18)
    const float cur = isFF ? __fadd_rn(SA, coC)
                           : __fadd_rn(__fadd_rn(xw, SA), coC);
    syn = __fadd_rn(__fmul_rn(coA, syn), cur);
    mem = __fsub_rn(__fadd_rn(__fmul_rn(coB, mem), syn), spk);
    spk = (mem > 1.0f) ? 1.0f : 0.0f;

    // per-wave ballot store: bits 0..31 = row 2wl, bits 32..63 = row 2wl+1
    const u64 B = __ballot(spk != 0.f);
    const int rowbase = 8 * rg + 2 * wl;
    if (!isFF) {
      if (l < 4) {
        const u32 word = (u32)(B >> (16 * l)) & 0xFFFFu;
        const int gs = rowbase + (l >> 1);
        const int wx = 2 * c + (l & 1);
        __hip_atomic_store(ring32 + (s & 1) * 4096 + gs * 32 + wx,
                           ((u32)(s + 1) << 16) | word,
                           __ATOMIC_RELAXED, __HIP_MEMORY_SCOPE_AGENT);
      } else if (l < 8) {
        const int l2 = l - 4;
        const u32 word = (u32)(B >> (16 * l2)) & 0xFFFFu;
        const int gs = rowbase + (l2 >> 1);
        const int wx = 2 * c + (l2 & 1);
        __hip_atomic_store(hist32 + (u64)s * 4096 + gs * 32 + wx,
                           ((u32)(s + 1) << 16) | word,
                           __ATOMIC_RELAXED, __HIP_MEMORY_SCOPE_AGENT);
      }
    } else {
      if (l < 4) {
        const u32 word = (u32)(B >> (16 * l)) & 0xFFFFu;
        const int gs = rowbase + (l >> 1);
        const int wx = 2 * c + (l & 1);
        spkb16[(u64)s * 4096 + gs * 32 + wx] = (u16)word;
      }
    }
    // no end-of-step barrier: staging rows are wave-private; poll gating
    // bounds skew (reaching store(s) requires poll(s) success, which requires
    // every clique wave of this row finished reading step s-2's slot).
  }
}

// ---------------------------------------------------------------------------
// k_c3: ff spike history (mask16 words) @ W_mu/W_lv readout, + bias.
// Same ascending-k FMA order (k = 16*wi + kk), split at wi=24 (k=384).
// ---------------------------------------------------------------------------
__global__ __launch_bounds__(256) void k_c3(
    const u16* __restrict__ spkb16, const float* __restrict__ WT,
    const float* __restrict__ bmu, const float* __restrict__ blv,
    float* __restrict__ c3)
{
  __shared__ __align__(8) u16 Bc[32][36];  // [row-local][32 w16, pad 36]
  const int tid   = threadIdx.x;
  const int rows0 = blockIdx.x * 32;

  {
    const int r = tid >> 3, gq = tid & 7;   // 32 rows x 8B
    const u64 vv = *(const u64*)(spkb16 + (u64)(rows0 + r) * 32 + 4 * gq);
    *(u64*)&Bc[r][4 * gq] = vv;
  }
  __syncthreads();

  const int j  = tid & 127;
  const int rh = tid >> 7;
  const float bias = (j < 64) ? bmu[j] : blv[j - 64];

  float accA[16], accB[16];
#pragma unroll
  for (int r = 0; r < 16; ++r) { accA[r] = 0.f; accB[r] = 0.f; }

  for (int wi = 0; wi < 24; ++wi) {   // k = 16*wi + kk < 384
    u16 wrow[16];
#pragma unroll
    for (int r = 0; r < 16; ++r) wrow[r] = Bc[rh * 16 + r][wi];
    const float* wpp = WT + (wi * 16) * 128 + j;
#pragma unroll
    for (int kk = 0; kk < 16; ++kk) {
      const float wvv = wpp[kk * 128];
#pragma unroll
      for (int r = 0; r < 16; ++r) {
        const float b = (float)((wrow[r] >> kk) & 1u);
        accA[r] = __builtin_fmaf(b, wvv, accA[r]);
      }
    }
  }
  for (int wi = 24; wi < 32; ++wi) {  // k >= 384
    u16 wrow[16];
#pragma unroll
    for (int r = 0; r < 16; ++r) wrow[r] = Bc[rh * 16 + r][wi];
    const float* wpp = WT + (wi * 16) * 128 + j;
#pragma unroll
    for (int kk = 0; kk < 16; ++kk) {
      const float wvv = wpp[kk * 128];
#pragma unroll
      for (int r = 0; r < 16; ++r) {
        const float b = (float)((wrow[r] >> kk) & 1u);
        accB[r] = __builtin_fmaf(b, wvv, accB[r]);
      }
    }
  }

#pragma unroll
  for (int r = 0; r < 16; ++r)
    c3[(u64)(rows0 + rh * 16 + r) * 128 + j] =
        __fadd_rn(__fadd_rn(accA[r], accB[r]), bias);
}

// ---------------------------------------------------------------------------
__global__ __launch_bounds__(256) void k_scan(
    const float* __restrict__ c3,
    const float* __restrict__ beta_mu, const float* __restrict__ beta_lv,
    float* __restrict__ Mem)
{
  const int tid = blockIdx.x * 256 + threadIdx.x;
  const int n = tid >> 7, ap = tid & 127;
  const float beta = (ap < 64) ? beta_mu[ap] : beta_lv[ap - 64];
  const float* src = c3 + n * 128 + ap;
  float* dst = Mem + n * 128 + ap;
  float mem = 0.0f;
  for (int t = 0; t < 512; ++t) {
    mem = __fadd_rn(__fmul_rn(beta, mem), src[(u64)t * 16384]);
    dst[(u64)t * 16384] = mem;
  }
}

// ---------------------------------------------------------------------------
__global__ __launch_bounds__(256) void k_out(
    const float* __restrict__ Mem,
    const float* __restrict__ Wmu_out, const float* __restrict__ Wlv_out,
    float* __restrict__ out)
{
  const int tid = blockIdx.x * 256 + threadIdx.x;
  const int a = tid & 7;
  const int n = (tid >> 3) & 127;
  const int t = (tid >> 10) & 255;
  const int kind = tid >> 18;
  const float* wv = ((kind == 0) ? Wmu_out : Wlv_out) + a * 64;
  const float* s0 = Mem + ((u64)(2 * t) * 128 + n) * 128 + kind * 64;
  const float* s1 = Mem + ((u64)(2 * t + 1) * 128 + n) * 128 + kind * 64;
  float mu0 = 0.0f, mu1 = 0.0f;
#pragma unroll 8
  for (int q = 0; q < 64; ++q) mu0 = __builtin_fmaf(s0[q], wv[q], mu0);
#pragma unroll 8
  for (int q = 0; q < 64; ++q) mu1 = __builtin_fmaf(s1[q], wv[q], mu1);
  out[tid] = __fmul_rn(__fadd_rn(mu0, mu1), 0.5f);
}

// ---------------------------------------------------------------------------
extern "C" void kernel_launch(void* const* d_in, const int* in_sizes, int n_in,
                              void* d_out, int out_size, void* d_ws, size_t ws_size,
                              hipStream_t stream) {
  (void)in_sizes; (void)n_in; (void)out_size;
  if (ws_size < WS_NEED) return;

  const float* state     = (const float*)d_in[0];
  const float* target    = (const float*)d_in[1];
  const float* W_rec_in  = (const float*)d_in[2];
  const float* b_rec_in  = (const float*)d_in[3];
  const float* W_rec     = (const float*)d_in[4];
  const float* b_rec     = (const float*)d_in[5];
  const float* alpha_rec = (const float*)d_in[6];
  const float* beta_rec  = (const float*)d_in[7];
  const float* W_ff_in   = (const float*)d_in[8];
  const float* b_ff_in   = (const float*)d_in[9];
  const float* alpha_ff  = (const float*)d_in[10];
  const float* beta_ff   = (const float*)d_in[11];
  const float* W_mu_in   = (const float*)d_in[12];
  const float* b_mu_in   = (const float*)d_in[13];
  const float* beta_mu   = (const float*)d_in[14];
  const float* W_mu_out  = (const float*)d_in[15];
  const float* W_lv_in   = (const float*)d_in[16];
  const float* b_lv_in   = (const float*)d_in[17];
  const float* beta_lv   = (const float*)d_in[18];
  const float* W_lv_out  = (const float*)d_in[19];

  char* ws = (char*)d_ws;
  float* XW    = (float*)(ws + XW_OFF);
  float* c3    = (float*)(ws + C3_OFF);
  float* Mem   = (float*)(ws + MEM_OFF);
  u32*   ring32= (u32*)  (ws + RING_OFF);
  u32*   hist32= (u32*)  (ws + HIST_OFF);
  u16*   spkb16= (u16*)  (ws + SPKB_OFF);
  float* WT    = (float*)(ws + WT_OFF);
  float* WinT  = (float*)(ws + WINT_OFF);

  // zero the tagged regions so tags (>=1) can never false-match poison
  hipMemsetAsync(ws + RING_OFF, 0, 32768, stream);
  hipMemsetAsync(ws + HIST_OFF, 0, 8388608, stream);

  hipLaunchKernelGGL(k_prepT, dim3(512), dim3(256), 0, stream,
                     W_rec_in, W_mu_in, W_lv_in, WinT, WT);
  hipLaunchKernelGGL(k_xw, dim3(2048), dim3(256), 0, stream,
                     state, target, WinT, b_rec_in, XW);
  hipLaunchKernelGGL(k_rec, dim3(256), dim3(512), 0, stream,
                     XW, W_rec, W_ff_in,
                     alpha_rec, beta_rec, b_rec,
                     b_ff_in, alpha_ff, beta_ff, ring32, hist32, spkb16);
  hipLaunchKernelGGL(k_c3, dim3(2048), dim3(256), 0, stream,
                     spkb16, WT, b_mu_in, b_lv_in, c3);
  hipLaunchKernelGGL(k_scan, dim3(64), dim3(256), 0, stream,
                     c3, beta_mu, beta_lv, Mem);
  hipLaunchKernelGGL(k_out, dim3(2048), dim3(256), 0, stream,
                     Mem, W_mu_out, W_lv_out, (float*)d_out);
}